// Round 4
// baseline (125.747 us; speedup 1.0000x reference)
//
#include <hip/hip_runtime.h>
#include <stdint.h>

typedef __bf16 bf16x8 __attribute__((ext_vector_type(8)));
typedef __bf16 bf16x2 __attribute__((ext_vector_type(2)));
typedef float f32x16 __attribute__((ext_vector_type(16)));

#define CC 64
#define HH 64
#define WW 64
#define OO 128
#define BB 4

// Product table t=0..24: 20 orbit reps (i+j<8) + 5 reflection-fixed (i+j=8).
__device__ constexpr int TI[25] = {0,0,0,0,0,0,0,0, 1,1,1,1,1,1, 2,2,2,2, 3,3, 0,1,2,3,4};
__device__ constexpr int TJ[25] = {0,1,2,3,4,5,6,7, 1,2,3,4,5,6, 2,3,4,5, 3,4, 8,7,6,5,4};

__device__ __forceinline__ unsigned int pack_bf16(float a, float b) {
#if __has_builtin(__builtin_amdgcn_cvt_pk_bf16_f32)
  bf16x2 r = __builtin_amdgcn_cvt_pk_bf16_f32(a, b);
  return __builtin_bit_cast(unsigned int, r);
#else
  unsigned int ua = __float_as_uint(a) + 0x8000u;
  unsigned int ub = __float_as_uint(b) + 0x8000u;
  return (ua >> 16) | (ub & 0xFFFF0000u);
#endif
}

// weight value for (n, c, half h, recipe index u in 0..31)  [R3-verified]
__device__ float wval(const float* __restrict__ wl, const float* __restrict__ wv,
                      int n, int c, int h, int u) {
  if (u < 7) {
    if (h == 0) return wl[(n * CC + c) * 9 + u];
    int k = 8 - u;
    return (u < 2) ? wl[(n * CC + c) * 9 + k] : 0.f;
  }
  int tt = u - 7;
  int a = TI[tt], bq = TJ[tt];
  if (h == 0) return wv[((n * CC + c) * 9 + a) * 9 + bq];
  if (tt >= 20) return 0.f;
  int a2 = 8 - bq, b2 = 8 - a;
  return wv[((n * CC + c) * 9 + a2) * 9 + b2];
}

// ---- prep: Wt as uint32[(((c*4+ot)*4+ks)*64 + lane)*4 + epair]  [R3-verified] ----
__global__ void prep_kernel(const float* __restrict__ wl, const float* __restrict__ wv,
                            unsigned int* __restrict__ Wt) {
  int t = blockIdx.x * 256 + threadIdx.x;
  if (t >= CC * 4 * 4 * 64 * 4) return;
  int ep = t & 3;
  int lane = (t >> 2) & 63;
  int ks = (t >> 8) & 3;
  int ot = (t >> 10) & 3;
  int c = t >> 12;
  int n = ot * 32 + (lane & 31);
  int h = lane >> 5;
  int u0 = ks * 8 + ep * 2;
  float v0 = wval(wl, wv, n, c, h, u0);
  float v1 = wval(wl, wv, n, c, h, u0 + 1);
  Wt[t] = pack_bf16(v0, v1);
}

// ---- main kernel ----
// grid 256 = (b,y); block 1024 = 16 waves = (otp in 2) x (ch in 8)
// wave: o in [otp*64, otp*64+64) (2 MFMA m-tiles), both x-tiles, c in [ch*8, ch*8+8)
__global__ __launch_bounds__(1024) void qconv_kernel(
    const float* __restrict__ img, const unsigned int* __restrict__ Wt,
    const float* __restrict__ bias, float* __restrict__ out) {
  // img slab [c][r][s], s = x+1 (66 wide, zero guards at s=0,65): 50688 B.
  // Reused as out_s[128][64] f32 accumulator (32 KB) in the epilogue.
  __shared__ float smem[CC * 3 * 66];

  const int t = threadIdx.x;
  const int lane = t & 63;
  const int wq = t >> 6;
  const int otp = wq & 1;
  const int ch = wq >> 1;
  const int n5 = lane & 31;
  const int h = lane >> 5;
  const int b = blockIdx.x >> 6;
  const int y = blockIdx.x & 63;

  // ---- stage image slab once (zero-padded; handles all OOB) ----
  {
    const int total = CC * 3 * 66;  // 12672
    for (int idx = t; idx < total; idx += 1024) {
      int c = idx / 198;
      int w = idx - c * 198;
      int r = w / 66;
      int s = w - r * 66;
      int xx = s - 1;
      int yy = y + r - 1;
      float v = 0.f;
      if ((unsigned)xx < 64u && (unsigned)yy < 64u)
        v = img[((b * CC + c) * HH + yy) * WW + xx];
      smem[idx] = v;
    }
  }
  __syncthreads();

  f32x16 acc[2][2];
#pragma unroll
  for (int io = 0; io < 2; ++io)
#pragma unroll
    for (int xt = 0; xt < 2; ++xt)
#pragma unroll
      for (int i = 0; i < 16; ++i) acc[io][xt][i] = 0.f;

  const int c0 = ch * 8;
#pragma unroll 1
  for (int c = c0; c < c0 + 8; ++c) {
    // ---- build both x-tile B-frags from LDS (immediate-offset reads) ----
    uint4 bf[2][4];
#pragma unroll
    for (int xt = 0; xt < 2; ++xt) {
      const int xb = xt * 32 + n5;           // slot of x-1 is xb, x is xb+1, x+1 is xb+2
      float pv[9];
#pragma unroll
      for (int r = 0; r < 3; ++r)
#pragma unroll
        for (int d = 0; d < 3; ++d)
          pv[r * 3 + d] = smem[(c * 3 + r) * 66 + xb + d];
      float q[9];
#pragma unroll
      for (int k = 0; k < 9; ++k) q[k] = h ? pv[8 - k] : pv[k];
      unsigned int pk[16];
#pragma unroll
      for (int i = 0; i < 16; ++i) {
        const int u0 = 2 * i, u1 = 2 * i + 1;
        float v0 = (u0 < 7) ? q[u0] : q[TI[u0 - 7]] * q[TJ[u0 - 7]];
        float v1 = (u1 < 7) ? q[u1] : q[TI[u1 - 7]] * q[TJ[u1 - 7]];
        pk[i] = pack_bf16(v0, v1);
      }
#pragma unroll
      for (int ks = 0; ks < 4; ++ks)
        bf[xt][ks] = make_uint4(pk[4 * ks], pk[4 * ks + 1], pk[4 * ks + 2], pk[4 * ks + 3]);
    }

    // ---- A direct from global (each frag read by exactly one wave) ----
    const unsigned int* wb = Wt + (c * 16 + otp * 8) * 256 + lane * 4;
#pragma unroll
    for (int ks = 0; ks < 4; ++ks) {
#pragma unroll
      for (int io = 0; io < 2; ++io) {
        uint4 araw = *(const uint4*)(wb + (io * 4 + ks) * 256);
        bf16x8 af = __builtin_bit_cast(bf16x8, araw);
        acc[io][0] = __builtin_amdgcn_mfma_f32_32x32x16_bf16(
            af, __builtin_bit_cast(bf16x8, bf[0][ks]), acc[io][0], 0, 0, 0);
        acc[io][1] = __builtin_amdgcn_mfma_f32_32x32x16_bf16(
            af, __builtin_bit_cast(bf16x8, bf[1][ks]), acc[io][1], 0, 0, 0);
      }
    }
  }

  // ---- epilogue: 8-round cross-ch accumulation into reused LDS ----
  __syncthreads();                 // all waves done with img slab
  float* out_s = smem;             // [o][x] 128x64 f32
#pragma unroll 1
  for (int rr = 0; rr < 8; ++rr) {
    if (ch == rr) {
#pragma unroll
      for (int io = 0; io < 2; ++io)
#pragma unroll
        for (int xt = 0; xt < 2; ++xt)
#pragma unroll
          for (int r = 0; r < 16; ++r) {
            int o = (otp * 2 + io) * 32 + (r & 3) + 8 * (r >> 2) + 4 * h;  // 32x32 C/D (m74/m101)
            int x = xt * 32 + n5;
            float v = acc[io][xt][r];
            if (rr == 0) out_s[o * 64 + x] = v;
            else out_s[o * 64 + x] += v;
          }
    }
    __syncthreads();
  }

  // ---- store: thread t -> o = t/8, 8 consecutive x ----
  {
    int o = t >> 3;
    int x0 = (t & 7) * 8;
    float bo = bias[o];
    float4 v0 = *(const float4*)&out_s[o * 64 + x0];
    float4 v1 = *(const float4*)&out_s[o * 64 + x0 + 4];
    v0.x += bo; v0.y += bo; v0.z += bo; v0.w += bo;
    v1.x += bo; v1.y += bo; v1.z += bo; v1.w += bo;
    float* op = out + ((b * OO + o) * HH + y) * WW + x0;
    *(float4*)op = v0;
    *(float4*)(op + 4) = v1;
  }
}

extern "C" void kernel_launch(void* const* d_in, const int* in_sizes, int n_in,
                              void* d_out, int out_size, void* d_ws, size_t ws_size,
                              hipStream_t stream) {
  const float* image = (const float*)d_in[0];
  const float* wl = (const float*)d_in[1];
  const float* wv = (const float*)d_in[2];
  const float* bias = (const float*)d_in[3];
  float* out = (float*)d_out;
  unsigned int* Wt = (unsigned int*)d_ws;  // 262144 uints = 1 MB

  int prep_elems = CC * 4 * 4 * 64 * 4;    // 262144
  prep_kernel<<<(prep_elems + 255) / 256, 256, 0, stream>>>(wl, wv, Wt);
  qconv_kernel<<<BB * HH, 1024, 0, stream>>>(image, Wt, bias, out);
}

// Round 5
// 108.023 us; speedup vs baseline: 1.1641x; 1.1641x over previous
//
#include <hip/hip_runtime.h>
#include <stdint.h>

typedef __bf16 bf16x8 __attribute__((ext_vector_type(8)));
typedef __bf16 bf16x2 __attribute__((ext_vector_type(2)));
typedef float f32x16 __attribute__((ext_vector_type(16)));

#define CC 64
#define HH 64
#define WW 64
#define OO 128
#define BB 4

// Product table t=0..24: 20 orbit reps (i+j<8) + 5 reflection-fixed (i+j=8).
__device__ constexpr int TI[25] = {0,0,0,0,0,0,0,0, 1,1,1,1,1,1, 2,2,2,2, 3,3, 0,1,2,3,4};
__device__ constexpr int TJ[25] = {0,1,2,3,4,5,6,7, 1,2,3,4,5,6, 2,3,4,5, 3,4, 8,7,6,5,4};

__device__ __forceinline__ unsigned int pack_bf16(float a, float b) {
#if __has_builtin(__builtin_amdgcn_cvt_pk_bf16_f32)
  bf16x2 r = __builtin_amdgcn_cvt_pk_bf16_f32(a, b);
  return __builtin_bit_cast(unsigned int, r);
#else
  unsigned int ua = __float_as_uint(a) + 0x8000u;
  unsigned int ub = __float_as_uint(b) + 0x8000u;
  return (ua >> 16) | (ub & 0xFFFF0000u);
#endif
}

// weight value for (n, c, half h, recipe index u in 0..31)  [R3/R4-verified]
__device__ float wval(const float* __restrict__ wl, const float* __restrict__ wv,
                      int n, int c, int h, int u) {
  if (u < 7) {
    if (h == 0) return wl[(n * CC + c) * 9 + u];
    int k = 8 - u;
    return (u < 2) ? wl[(n * CC + c) * 9 + k] : 0.f;
  }
  int tt = u - 7;
  int a = TI[tt], bq = TJ[tt];
  if (h == 0) return wv[((n * CC + c) * 9 + a) * 9 + bq];
  if (tt >= 20) return 0.f;
  int a2 = 8 - bq, b2 = 8 - a;
  return wv[((n * CC + c) * 9 + a2) * 9 + b2];
}

// ---- prep: Wt as uint32[(((c*4+ot)*4+ks)*64 + lane)*4 + epair]  [R3/R4-verified] ----
__global__ void prep_kernel(const float* __restrict__ wl, const float* __restrict__ wv,
                            unsigned int* __restrict__ Wt) {
  int t = blockIdx.x * 256 + threadIdx.x;
  if (t >= CC * 4 * 4 * 64 * 4) return;
  int ep = t & 3;
  int lane = (t >> 2) & 63;
  int ks = (t >> 8) & 3;
  int ot = (t >> 10) & 3;
  int c = t >> 12;
  int n = ot * 32 + (lane & 31);
  int h = lane >> 5;
  int u0 = ks * 8 + ep * 2;
  float v0 = wval(wl, wv, n, c, h, u0);
  float v1 = wval(wl, wv, n, c, h, u0 + 1);
  Wt[t] = pack_bf16(v0, v1);
}

// ---- main kernel ----
// grid 256 = (b,y); block 1024 = 16 waves = (ot in 4) x (ch in 4)
// wave: one 32-o tile (acc 32 VGPR for both x-tiles), c-range of 16.
// A-frags: each (c,ot) fragment loaded by exactly one wave (L2 floor: 1 MB/block).
__global__ __launch_bounds__(1024, 4) void qconv_kernel(
    const float* __restrict__ img, const unsigned int* __restrict__ Wt,
    const float* __restrict__ bias, float* __restrict__ out) {
  // img slab [c][r][s], s = x+1 (66 wide, zero guards): 50688 B.
  // Reused as out_s[128][64] f32 accumulator (32 KB) in the epilogue.
  __shared__ float smem[CC * 3 * 66];

  const int t = threadIdx.x;
  const int lane = t & 63;
  const int wq = t >> 6;
  const int ot = wq & 3;
  const int ch = wq >> 2;
  const int n5 = lane & 31;
  const int h = lane >> 5;
  const int b = blockIdx.x >> 6;
  const int y = blockIdx.x & 63;

  // ---- stage image slab once (zero-padded; handles all OOB) ----
  {
    const int total = CC * 3 * 66;  // 12672
    for (int idx = t; idx < total; idx += 1024) {
      int c = idx / 198;
      int w = idx - c * 198;
      int r = w / 66;
      int s = w - r * 66;
      int xx = s - 1;
      int yy = y + r - 1;
      float v = 0.f;
      if ((unsigned)xx < 64u && (unsigned)yy < 64u)
        v = img[((b * CC + c) * HH + yy) * WW + xx];
      smem[idx] = v;
    }
  }

  // per-lane reflected patch addresses (element units, within one channel's 198):
  // q[r*3+d] = slab[(h?2-r:r)*66 + (h?2-d:d) + n5]   (xt adds +32)
  int aidx[9];
#pragma unroll
  for (int k = 0; k < 9; ++k) {
    int r = k / 3, d = k - 3 * r;
    int rr = h ? 2 - r : r;
    int dd = h ? 2 - d : d;
    aidx[k] = rr * 66 + dd + n5;
  }

  __syncthreads();

  f32x16 acc[2];
#pragma unroll
  for (int xt = 0; xt < 2; ++xt)
#pragma unroll
    for (int i = 0; i < 16; ++i) acc[xt][i] = 0.f;

  const int c0 = ch * 16;
#pragma unroll 2
  for (int ci = 0; ci < 16; ++ci) {
    const int c = c0 + ci;
    // ---- A-frags for this (c, ot): 4 x 16B from global (L2-resident) ----
    const unsigned int* wb = Wt + (c * 16 + ot * 4) * 256 + lane * 4;
    uint4 araw[4];
#pragma unroll
    for (int ks = 0; ks < 4; ++ks) araw[ks] = *(const uint4*)(wb + ks * 256);

    const int cbase = c * 198;
#pragma unroll
    for (int xt = 0; xt < 2; ++xt) {
      // ---- build B-frag: 9 LDS reads (reflection pre-baked), 25 mul, 16 packs ----
      float q[9];
#pragma unroll
      for (int k = 0; k < 9; ++k) q[k] = smem[cbase + aidx[k] + xt * 32];
      unsigned int pk[16];
#pragma unroll
      for (int i = 0; i < 16; ++i) {
        const int u0 = 2 * i, u1 = 2 * i + 1;
        float v0 = (u0 < 7) ? q[u0] : q[TI[u0 - 7]] * q[TJ[u0 - 7]];
        float v1 = (u1 < 7) ? q[u1] : q[TI[u1 - 7]] * q[TJ[u1 - 7]];
        pk[i] = pack_bf16(v0, v1);
      }
#pragma unroll
      for (int ks = 0; ks < 4; ++ks) {
        uint4 braw = make_uint4(pk[4 * ks], pk[4 * ks + 1], pk[4 * ks + 2], pk[4 * ks + 3]);
        acc[xt] = __builtin_amdgcn_mfma_f32_32x32x16_bf16(
            __builtin_bit_cast(bf16x8, araw[ks]),
            __builtin_bit_cast(bf16x8, braw), acc[xt], 0, 0, 0);
      }
    }
  }

  // ---- epilogue: 4-round cross-ch accumulation into reused LDS ----
  __syncthreads();                 // all waves done reading img slab
  float* out_s = smem;             // [o][x] 128x64 f32
#pragma unroll 1
  for (int rr = 0; rr < 4; ++rr) {
    if (ch == rr) {
#pragma unroll
      for (int xt = 0; xt < 2; ++xt)
#pragma unroll
        for (int r = 0; r < 16; ++r) {
          int o = ot * 32 + (r & 3) + 8 * (r >> 2) + 4 * h;  // 32x32 C/D (m74/m101)
          int x = xt * 32 + n5;
          float v = acc[xt][r];
          if (rr == 0) out_s[o * 64 + x] = v;
          else out_s[o * 64 + x] += v;
        }
    }
    __syncthreads();
  }

  // ---- store: thread t -> o = t/8, 8 consecutive x ----
  {
    int o = t >> 3;
    int x0 = (t & 7) * 8;
    float bo = bias[o];
    float4 v0 = *(const float4*)&out_s[o * 64 + x0];
    float4 v1 = *(const float4*)&out_s[o * 64 + x0 + 4];
    v0.x += bo; v0.y += bo; v0.z += bo; v0.w += bo;
    v1.x += bo; v1.y += bo; v1.z += bo; v1.w += bo;
    float* op = out + ((b * OO + o) * HH + y) * WW + x0;
    *(float4*)op = v0;
    *(float4*)(op + 4) = v1;
  }
}

extern "C" void kernel_launch(void* const* d_in, const int* in_sizes, int n_in,
                              void* d_out, int out_size, void* d_ws, size_t ws_size,
                              hipStream_t stream) {
  const float* image = (const float*)d_in[0];
  const float* wl = (const float*)d_in[1];
  const float* wv = (const float*)d_in[2];
  const float* bias = (const float*)d_in[3];
  float* out = (float*)d_out;
  unsigned int* Wt = (unsigned int*)d_ws;  // 262144 uints = 1 MB

  int prep_elems = CC * 4 * 4 * 64 * 4;    // 262144
  prep_kernel<<<(prep_elems + 255) / 256, 256, 0, stream>>>(wl, wv, Wt);
  qconv_kernel<<<BB * HH, 1024, 0, stream>>>(image, Wt, bias, out);
}

// Round 7
// 97.584 us; speedup vs baseline: 1.2886x; 1.1070x over previous
//
#include <hip/hip_runtime.h>
#include <stdint.h>

typedef __bf16 bf16x8 __attribute__((ext_vector_type(8)));
typedef __bf16 bf16x2 __attribute__((ext_vector_type(2)));
typedef float f32x16 __attribute__((ext_vector_type(16)));

#define CC 64
#define HH 64
#define WW 64
#define OO 128
#define BB 4

// Product table t=0..24: 20 orbit reps (i+j<8) + 5 reflection-fixed (i+j=8).
// NOTE: slot 31 (t=24) is the (4,4) center-square term — it is REAL (R6 bug).
__device__ constexpr int TI[25] = {0,0,0,0,0,0,0,0, 1,1,1,1,1,1, 2,2,2,2, 3,3, 0,1,2,3,4};
__device__ constexpr int TJ[25] = {0,1,2,3,4,5,6,7, 1,2,3,4,5,6, 2,3,4,5, 3,4, 8,7,6,5,4};

// software RNE pack (lo = a, hi = b) — prep only (exact, cost irrelevant there).
__device__ __forceinline__ unsigned int pack_rne(float a, float b) {
  unsigned int ua = __float_as_uint(a);
  ua = ua + 0x7FFFu + ((ua >> 16) & 1u);
  unsigned int ub = __float_as_uint(b);
  ub = ub + 0x7FFFu + ((ub >> 16) & 1u);
  return (ua >> 16) | (ub & 0xFFFF0000u);
}

// 1-instruction pack (lo = a, hi = b) for the hot loop:
// prefer HW RNE cvt_pk; fall back to truncating v_perm_b32.
__device__ __forceinline__ unsigned int pack_fast(float a, float b) {
#if __has_builtin(__builtin_amdgcn_cvt_pk_bf16_f32)
  bf16x2 r = __builtin_amdgcn_cvt_pk_bf16_f32(a, b);
  return __builtin_bit_cast(unsigned int, r);
#else
  // D = [b.hi16, a.hi16]: sel 0x07060302 over {S0=b, S1=a}
  return __builtin_amdgcn_perm(__float_as_uint(b), __float_as_uint(a), 0x07060302u);
#endif
}

// weight value for (n, c, half h, recipe index u in 0..31)  [R3-R5 verified]
__device__ float wval(const float* __restrict__ wl, const float* __restrict__ wv,
                      int n, int c, int h, int u) {
  if (u < 7) {
    if (h == 0) return wl[(n * CC + c) * 9 + u];
    int k = 8 - u;
    return (u < 2) ? wl[(n * CC + c) * 9 + k] : 0.f;
  }
  int tt = u - 7;
  int a = TI[tt], bq = TJ[tt];
  if (h == 0) return wv[((n * CC + c) * 9 + a) * 9 + bq];
  if (tt >= 20) return 0.f;
  int a2 = 8 - bq, b2 = 8 - a;
  return wv[((n * CC + c) * 9 + a2) * 9 + b2];
}

// ---- prep: Wt as uint32[(((c*4+ot)*4+ks)*64 + lane)*4 + epair]  [R3-R5 verified] ----
__global__ void prep_kernel(const float* __restrict__ wl, const float* __restrict__ wv,
                            unsigned int* __restrict__ Wt) {
  int t = blockIdx.x * 256 + threadIdx.x;
  if (t >= CC * 4 * 4 * 64 * 4) return;
  int ep = t & 3;
  int lane = (t >> 2) & 63;
  int ks = (t >> 8) & 3;
  int ot = (t >> 10) & 3;
  int c = t >> 12;
  int n = ot * 32 + (lane & 31);
  int h = lane >> 5;
  int u0 = ks * 8 + ep * 2;
  float v0 = wval(wl, wv, n, c, h, u0);
  float v1 = wval(wl, wv, n, c, h, u0 + 1);
  Wt[t] = pack_rne(v0, v1);
}

// ---- main kernel ----
// grid 256 = (b,y); block 1024 = 16 waves = (ot in 4) x (ch in 4)
// wave: one 32-o tile, both x-tiles, 16 channels. A-frags read by exactly one wave.
__global__ __launch_bounds__(1024, 4) void qconv_kernel(
    const float* __restrict__ img, const unsigned int* __restrict__ Wt,
    const float* __restrict__ bias, float* __restrict__ out) {
  // img slab [c][r][s], s = x+1 (66 wide, zero guards): 50688 B.
  // Reused as out_s[128][64] f32 accumulator (32 KB) in the epilogue.
  __shared__ float smem[CC * 3 * 66];

  const int t = threadIdx.x;
  const int lane = t & 63;
  const int wq = t >> 6;
  const int ot = wq & 3;
  const int ch = wq >> 2;
  const int n5 = lane & 31;
  const int h = lane >> 5;
  const int b = blockIdx.x >> 6;
  const int y = blockIdx.x & 63;

  // ---- stage image slab once (zero-padded; handles all OOB) ----
  {
    const int total = CC * 3 * 66;  // 12672
    for (int idx = t; idx < total; idx += 1024) {
      int c = idx / 198;
      int w = idx - c * 198;
      int r = w / 66;
      int s = w - r * 66;
      int xx = s - 1;
      int yy = y + r - 1;
      float v = 0.f;
      if ((unsigned)xx < 64u && (unsigned)yy < 64u)
        v = img[((b * CC + c) * HH + yy) * WW + xx];
      smem[idx] = v;
    }
  }

  const int c0 = ch * 16;

  // 9 persistent per-lane LDS base pointers, h-reflection baked in.
  const float* qp[9];
#pragma unroll
  for (int k = 0; k < 9; ++k) {
    int r = k / 3, d = k - 3 * r;
    int rr = h ? 2 - r : r;
    int dd = h ? 2 - d : d;
    qp[k] = smem + c0 * 198 + rr * 66 + dd + n5;
  }
  // A-frag pointer: uint4 index = c*1024 + ot*256 + ks*64 + lane
  const uint4* wb = (const uint4*)Wt + (size_t)c0 * 1024 + ot * 256 + lane;

  __syncthreads();

  f32x16 acc[2];
#pragma unroll
  for (int xt = 0; xt < 2; ++xt)
#pragma unroll
    for (int i = 0; i < 16; ++i) acc[xt][i] = 0.f;

#pragma unroll 1
  for (int cg = 0; cg < 4; ++cg) {
#pragma unroll
    for (int i = 0; i < 4; ++i) {
      // A-frags for this channel (L2-resident, unique per wave)
      uint4 araw[4];
#pragma unroll
      for (int ks = 0; ks < 4; ++ks) araw[ks] = wb[i * 1024 + ks * 64];

#pragma unroll
      for (int xt = 0; xt < 2; ++xt) {
        // 9 LDS reads, all immediate offsets off persistent base regs
        float q[9];
#pragma unroll
        for (int k = 0; k < 9; ++k) q[k] = qp[k][i * 198 + xt * 32];
        // 32 slot values: 7 linear + 25 products (slot 31 = q4*q4, REAL)
        float vals[32];
#pragma unroll
        for (int u = 0; u < 7; ++u) vals[u] = q[u];
#pragma unroll
        for (int p = 0; p < 25; ++p) vals[7 + p] = q[TI[p]] * q[TJ[p]];
#pragma unroll
        for (int ks = 0; ks < 4; ++ks) {
          uint4 br;
          br.x = pack_fast(vals[ks * 8 + 0], vals[ks * 8 + 1]);
          br.y = pack_fast(vals[ks * 8 + 2], vals[ks * 8 + 3]);
          br.z = pack_fast(vals[ks * 8 + 4], vals[ks * 8 + 5]);
          br.w = pack_fast(vals[ks * 8 + 6], vals[ks * 8 + 7]);
          acc[xt] = __builtin_amdgcn_mfma_f32_32x32x16_bf16(
              __builtin_bit_cast(bf16x8, araw[ks]),
              __builtin_bit_cast(bf16x8, br), acc[xt], 0, 0, 0);
        }
      }
    }
    // advance bases by 4 channels
#pragma unroll
    for (int k = 0; k < 9; ++k) qp[k] += 4 * 198;
    wb += 4 * 1024;
  }

  // ---- epilogue: 4-round cross-ch accumulation into reused LDS ----
  __syncthreads();                 // all waves done reading img slab
  float* out_s = smem;             // [o][x] 128x64 f32
#pragma unroll 1
  for (int rr = 0; rr < 4; ++rr) {
    if (ch == rr) {
#pragma unroll
      for (int xt = 0; xt < 2; ++xt)
#pragma unroll
        for (int r = 0; r < 16; ++r) {
          int o = ot * 32 + (r & 3) + 8 * (r >> 2) + 4 * h;  // 32x32 C/D (m74/m101)
          int x = xt * 32 + n5;
          float v = acc[xt][r];
          if (rr == 0) out_s[o * 64 + x] = v;
          else out_s[o * 64 + x] += v;
        }
    }
    __syncthreads();
  }

  // ---- store: thread t -> o = t/8, 8 consecutive x ----
  {
    int o = t >> 3;
    int x0 = (t & 7) * 8;
    float bo = bias[o];
    float4 v0 = *(const float4*)&out_s[o * 64 + x0];
    float4 v1 = *(const float4*)&out_s[o * 64 + x0 + 4];
    v0.x += bo; v0.y += bo; v0.z += bo; v0.w += bo;
    v1.x += bo; v1.y += bo; v1.z += bo; v1.w += bo;
    float* op = out + ((b * OO + o) * HH + y) * WW + x0;
    *(float4*)op = v0;
    *(float4*)(op + 4) = v1;
  }
}

extern "C" void kernel_launch(void* const* d_in, const int* in_sizes, int n_in,
                              void* d_out, int out_size, void* d_ws, size_t ws_size,
                              hipStream_t stream) {
  const float* image = (const float*)d_in[0];
  const float* wl = (const float*)d_in[1];
  const float* wv = (const float*)d_in[2];
  const float* bias = (const float*)d_in[3];
  float* out = (float*)d_out;
  unsigned int* Wt = (unsigned int*)d_ws;  // 262144 uints = 1 MB

  int prep_elems = CC * 4 * 4 * 64 * 4;    // 262144
  prep_kernel<<<(prep_elems + 255) / 256, 256, 0, stream>>>(wl, wv, Wt);
  qconv_kernel<<<BB * HH, 1024, 0, stream>>>(image, Wt, bias, out);
}